// Round 9
// baseline (280.787 us; speedup 1.0000x reference)
//
#include <hip/hip_runtime.h>
#include <hip/hip_bf16.h>
#include <math.h>

#define BB 4
#define CC 128
#define HH 128
#define WWD 128
#define HWW 16384
#define PREC 17424  // 132*132 padded records per plane

typedef __attribute__((ext_vector_type(8))) short bf16x8;
typedef __attribute__((ext_vector_type(4))) float floatx4;
typedef __attribute__((ext_vector_type(4))) unsigned short us4;
typedef __attribute__((ext_vector_type(8))) unsigned short us8;

__device__ __forceinline__ float gelu_exact(float v) {
  return 0.5f * v * (1.0f + erff(v * 0.70710678118654752f));
}
__device__ __forceinline__ unsigned short f2us(float f) {
  union { float f; unsigned int u; } c; c.f = f;
  unsigned int u = c.u;
  return (unsigned short)((u + 0x7FFFu + ((u >> 16) & 1u)) >> 16);
}

// ---------------- Kernel Z: zero padded planes + bn2 stat accumulators ----
__global__ __launch_bounds__(256) void k_zero(
    unsigned short* __restrict__ xp, float* __restrict__ part2) {
  if (blockIdx.x == 2178) { part2[threadIdx.x] = 0.f; return; }
  long i = ((long)blockIdx.x * 256 + threadIdx.x) * 8;
  us8 z = (us8)0;
  *(us8*)&xp[i] = z;
}

// ---------------- Kernel X: transpose x[:,0:32] -> xt[b][pixel][32] fp32 --
__global__ __launch_bounds__(256) void k_xt(
    const float* __restrict__ x, float* __restrict__ xt) {
  __shared__ float t[64 * 33];
  int bid = blockIdx.x;            // 1024: b = bid>>8, pg = bid&255
  int tid = threadIdx.x;
  int b = bid >> 8, pg = bid & 255;
  int c = tid >> 3, g8 = tid & 7;
  const float* xp = x + ((long)b * CC + c) * HWW + pg * 64 + g8 * 8;
  float4 v0 = *(const float4*)xp;
  float4 v1 = *(const float4*)(xp + 4);
  t[(g8 * 8 + 0) * 33 + c] = v0.x; t[(g8 * 8 + 1) * 33 + c] = v0.y;
  t[(g8 * 8 + 2) * 33 + c] = v0.z; t[(g8 * 8 + 3) * 33 + c] = v0.w;
  t[(g8 * 8 + 4) * 33 + c] = v1.x; t[(g8 * 8 + 5) * 33 + c] = v1.y;
  t[(g8 * 8 + 6) * 33 + c] = v1.z; t[(g8 * 8 + 7) * 33 + c] = v1.w;
  __syncthreads();
  int u = tid >> 2, q = tid & 3;
  float4 o0, o1;
  o0.x = t[u * 33 + q * 8 + 0]; o0.y = t[u * 33 + q * 8 + 1];
  o0.z = t[u * 33 + q * 8 + 2]; o0.w = t[u * 33 + q * 8 + 3];
  o1.x = t[u * 33 + q * 8 + 4]; o1.y = t[u * 33 + q * 8 + 5];
  o1.z = t[u * 33 + q * 8 + 6]; o1.w = t[u * 33 + q * 8 + 7];
  float* d = xt + ((long)b * HWW + pg * 64 + u) * 32 + q * 8;
  *(float4*)d = o0;
  *(float4*)(d + 4) = o1;
}

// ---------------- Kernel P: pack padded channels-last bf16 planes ---------
__global__ __launch_bounds__(256) void k_pack(
    const float* __restrict__ x, unsigned short* __restrict__ xp) {
  __shared__ float t[64 * 33];
  int bid = blockIdx.x;            // 2048 = which(2) x b(4) x pg(256)
  int tid = threadIdx.x;
  int which = bid >> 10, b = (bid >> 8) & 3, pg = bid & 255;
  int cbase = which ? 96 : 0;
  int c = tid >> 3, g8 = tid & 7;
  const float* xpr = x + ((long)b * CC + cbase + c) * HWW + pg * 64 + g8 * 8;
  float4 v0 = *(const float4*)xpr;
  float4 v1 = *(const float4*)(xpr + 4);
  t[(g8 * 8 + 0) * 33 + c] = v0.x; t[(g8 * 8 + 1) * 33 + c] = v0.y;
  t[(g8 * 8 + 2) * 33 + c] = v0.z; t[(g8 * 8 + 3) * 33 + c] = v0.w;
  t[(g8 * 8 + 4) * 33 + c] = v1.x; t[(g8 * 8 + 5) * 33 + c] = v1.y;
  t[(g8 * 8 + 6) * 33 + c] = v1.z; t[(g8 * 8 + 7) * 33 + c] = v1.w;
  __syncthreads();
  int u = tid >> 2, q = tid & 3;
  int p = pg * 64 + u;
  int yy = p >> 7, xx = p & 127;
  long rec = (long)(which * 4 + b) * PREC + (yy + 2) * 132 + xx + 2;
  us8 o;
#pragma unroll
  for (int k = 0; k < 8; k++) o[k] = f2us(t[u * 33 + q * 8 + k]);
  *(us8*)&xp[rec * 32 + q * 8] = o;
}

// ---------------- Kernel W2: conv weights -> MFMA B-fragment order --------
__global__ __launch_bounds__(256) void k_wprep2(
    const float* __restrict__ offw, const float* __restrict__ dilw,
    unsigned short* __restrict__ wob, unsigned short* __restrict__ w3b) {
  int t = blockIdx.x * 256 + threadIdx.x;  // 0..2303
  if (t >= 2304) return;
  int which = t >= 1152;
  int u = t - which * 1152;
  int lane = u & 63, tn = u >> 6;          // tn = tap*2 + nt
  int col = lane & 15, quad = lane >> 4;
  int tap = tn >> 1, nt = tn & 1;
  int n = nt * 16 + col;
  const float* W = which ? dilw : offw;
  int noc = which ? 32 : 18;
  unsigned short* d = (which ? w3b : wob) + (long)(tn * 64 + lane) * 8;
#pragma unroll
  for (int j = 0; j < 8; j++)
    d[j] = (n < noc) ? f2us(W[(long)n * 288 + (quad * 8 + j) * 9 + tap]) : (unsigned short)0;
}

// ---------------- Kernel A: offset conv 3x3 via MFMA implicit GEMM --------
__global__ __launch_bounds__(256) void k_offc_mm(
    const unsigned short* __restrict__ xp0, const unsigned short* __restrict__ wob,
    const float* __restrict__ bias, float* __restrict__ off) {
  int bid = blockIdx.x;
  int b = bid >> 7, yy = bid & 127;
  int tid = threadIdx.x;
  int lane = tid & 63, wv = tid >> 6;
  int row = lane & 15, quad = lane >> 4;
  const unsigned short* plane = xp0 + (long)b * PREC * 32;
  int xb = wv * 32;
  floatx4 Oa[2][2];
#pragma unroll
  for (int mt = 0; mt < 2; mt++)
#pragma unroll
    for (int nt = 0; nt < 2; nt++) Oa[mt][nt] = (floatx4)0.f;
#pragma unroll
  for (int t = 0; t < 9; t++) {
    int dy = t / 3 - 1, dx = t % 3 - 1;
    const unsigned short* rp = plane + ((long)(yy + 2 + dy) * 132 + 2 + dx + xb) * 32;
    bf16x8 A0 = *(const bf16x8*)&rp[row * 32 + quad * 8];
    bf16x8 A1 = *(const bf16x8*)&rp[(16 + row) * 32 + quad * 8];
#pragma unroll
    for (int nt = 0; nt < 2; nt++) {
      bf16x8 Bf = *(const bf16x8*)&wob[(long)((t * 2 + nt) * 64 + lane) * 8];
      Oa[0][nt] = __builtin_amdgcn_mfma_f32_16x16x32_bf16(A0, Bf, Oa[0][nt], 0, 0, 0);
      Oa[1][nt] = __builtin_amdgcn_mfma_f32_16x16x32_bf16(A1, Bf, Oa[1][nt], 0, 0, 0);
    }
  }
#pragma unroll
  for (int nt = 0; nt < 2; nt++) {
    int oc = nt * 16 + (lane & 15);
    if (oc < 18) {
      float bb = bias[oc];
#pragma unroll
      for (int mt = 0; mt < 2; mt++) {
        floatx4 v = Oa[mt][nt];
        v[0] += bb; v[1] += bb; v[2] += bb; v[3] += bb;
        long p = (long)(b * 18 + oc) * HWW + yy * 128 + xb + mt * 16 + quad * 4;
        *(floatx4*)&off[p] = v;
      }
    }
  }
}

// ---------------- Kernel D: dilated 3x3 conv via MFMA implicit GEMM -------
__global__ __launch_bounds__(256) void k_dil3_mm(
    const unsigned short* __restrict__ xp1, const unsigned short* __restrict__ w3b,
    const float* __restrict__ bias, float* __restrict__ y) {
  int bid = blockIdx.x;
  int b = bid >> 7, yy = bid & 127;
  int tid = threadIdx.x;
  int lane = tid & 63, wv = tid >> 6;
  int row = lane & 15, quad = lane >> 4;
  const unsigned short* plane = xp1 + (long)b * PREC * 32;
  int xb = wv * 32;
  floatx4 Oa[2][2];
#pragma unroll
  for (int mt = 0; mt < 2; mt++)
#pragma unroll
    for (int nt = 0; nt < 2; nt++) Oa[mt][nt] = (floatx4)0.f;
#pragma unroll
  for (int t = 0; t < 9; t++) {
    int dy = (t / 3 - 1) * 2, dx = (t % 3 - 1) * 2;
    const unsigned short* rp = plane + ((long)(yy + 2 + dy) * 132 + 2 + dx + xb) * 32;
    bf16x8 A0 = *(const bf16x8*)&rp[row * 32 + quad * 8];
    bf16x8 A1 = *(const bf16x8*)&rp[(16 + row) * 32 + quad * 8];
#pragma unroll
    for (int nt = 0; nt < 2; nt++) {
      bf16x8 Bf = *(const bf16x8*)&w3b[(long)((t * 2 + nt) * 64 + lane) * 8];
      Oa[0][nt] = __builtin_amdgcn_mfma_f32_16x16x32_bf16(A0, Bf, Oa[0][nt], 0, 0, 0);
      Oa[1][nt] = __builtin_amdgcn_mfma_f32_16x16x32_bf16(A1, Bf, Oa[1][nt], 0, 0, 0);
    }
  }
#pragma unroll
  for (int nt = 0; nt < 2; nt++) {
    int oc = nt * 16 + (lane & 15);
    int cp = 65 + 2 * oc;   // c = 96+oc -> (c%64)*2 + c/64
    float bb = bias[oc];
#pragma unroll
    for (int mt = 0; mt < 2; mt++) {
      floatx4 v = Oa[mt][nt];
      v[0] += bb; v[1] += bb; v[2] += bb; v[3] += bb;
      long p = ((long)b * CC + cp) * HWW + yy * 128 + xb + mt * 16 + quad * 4;
      *(floatx4*)&y[p] = v;
    }
  }
}

// ---------------- Kernel B: deformable depthwise, channels-last gathers ---
__global__ __launch_bounds__(256) void k_deform(
    const float* __restrict__ xt, const float* __restrict__ off,
    const float* __restrict__ dw, float* __restrict__ y) {
  __shared__ float wl[144];        // [k][16]
  int tid = threadIdx.x;
  int g = blockIdx.x * 256 + tid;
  int hf = g >> 16;                // uniform per block
  int pix = g & 65535;
  if (tid < 144) {
    int k = tid >> 4, q = tid & 15;
    wl[k * 16 + q] = dw[(hf * 16 + q) * 9 + k];
  }
  __syncthreads();
  int b = pix >> 14, p = pix & 16383;
  int i = p >> 7, j = p & 127;
  float acc[16];
#pragma unroll
  for (int q = 0; q < 16; q++) acc[q] = 0.f;
  const float* offb = off + (long)b * 18 * HWW + p;
  const float* xb = xt + (long)b * HWW * 32 + hf * 16;
  for (int k = 0; k < 9; k++) {
    float dy = offb[(long)(2 * k) * HWW];
    float dx = offb[(long)(2 * k + 1) * HWW];
    float ys = (float)i - 1.f + (float)(k / 3) + dy;
    float xs = (float)j - 1.f + (float)(k % 3) + dx;
    float y0 = floorf(ys), x0 = floorf(xs);
    float fy = ys - y0, fx = xs - x0;
    int iy0 = (int)y0, ix0 = (int)x0;
    int iy1 = iy0 + 1, ix1 = ix0 + 1;
    float wy0 = (1.f - fy) * ((iy0 >= 0 && iy0 <= 127) ? 1.f : 0.f);
    float wy1 = fy * ((iy1 >= 0 && iy1 <= 127) ? 1.f : 0.f);
    float wx0 = (1.f - fx) * ((ix0 >= 0 && ix0 <= 127) ? 1.f : 0.f);
    float wx1 = fx * ((ix1 >= 0 && ix1 <= 127) ? 1.f : 0.f);
    int cy0 = min(max(iy0, 0), 127), cy1 = min(max(iy1, 0), 127);
    int cx0 = min(max(ix0, 0), 127), cx1 = min(max(ix1, 0), 127);
    int ci[4] = {cy0 * 128 + cx0, cy0 * 128 + cx1, cy1 * 128 + cx0, cy1 * 128 + cx1};
    float cw[4] = {wy0 * wx0, wy0 * wx1, wy1 * wx0, wy1 * wx1};
    float v[16];
#pragma unroll
    for (int q = 0; q < 16; q++) v[q] = 0.f;
#pragma unroll
    for (int cn = 0; cn < 4; cn++) {
      const float* cp = xb + (long)ci[cn] * 32;
      float wc = cw[cn];
      float4 p0 = *(const float4*)cp;
      float4 p1 = *(const float4*)(cp + 4);
      float4 p2 = *(const float4*)(cp + 8);
      float4 p3 = *(const float4*)(cp + 12);
      v[0] += wc * p0.x;  v[1] += wc * p0.y;  v[2] += wc * p0.z;  v[3] += wc * p0.w;
      v[4] += wc * p1.x;  v[5] += wc * p1.y;  v[6] += wc * p1.z;  v[7] += wc * p1.w;
      v[8] += wc * p2.x;  v[9] += wc * p2.y;  v[10] += wc * p2.z; v[11] += wc * p2.w;
      v[12] += wc * p3.x; v[13] += wc * p3.y; v[14] += wc * p3.z; v[15] += wc * p3.w;
    }
    const float* wr = &wl[k * 16];
#pragma unroll
    for (int q = 0; q < 16; q++) acc[q] += wr[q] * v[q];
  }
#pragma unroll
  for (int q = 0; q < 16; q++) {
    int cp = 2 * (hf * 16 + q);
    y[((long)b * CC + cp) * HWW + p] = acc[q];
  }
}

// ---------------- Kernel C: depthwise 7x7, LDS-tiled ----------------------
__global__ __launch_bounds__(256) void k_dw7(
    const float* __restrict__ x, const float* __restrict__ w,
    const float* __restrict__ bias, float* __restrict__ y) {
  __shared__ float tile[22 * 136];
  __shared__ float wl[49];
  __shared__ float bsh;
  int bid = blockIdx.x;
  int b = bid >> 9, m = (bid >> 3) & 63, strip = bid & 7;
  int r0 = strip * 16;
  int tid = threadIdx.x;
  const float* xp = x + ((long)b * CC + 32 + m) * HWW;
  for (int idx = tid; idx < 2948; idx += 256) {
    int rr = idx / 134;
    int cc = idx - rr * 134 - 3;
    int gy = r0 - 3 + rr;
    float v = 0.f;
    if ((unsigned)gy < 128u && (unsigned)cc < 128u) v = xp[gy * 128 + cc];
    tile[rr * 136 + cc + 3] = v;
  }
  if (tid < 49) wl[tid] = w[m * 49 + tid];
  if (tid == 64) bsh = bias[m];
  __syncthreads();
  int j = tid & 127, s = tid >> 7;
  float acc[8];
#pragma unroll
  for (int o = 0; o < 8; o++) acc[o] = bsh;
#pragma unroll
  for (int kx = 0; kx < 7; kx++) {
#pragma unroll
    for (int rr = 0; rr < 14; rr++) {
      float v = tile[(s * 8 + rr) * 136 + j + kx];
      int olo = rr - 6 > 0 ? rr - 6 : 0;
      int ohi = rr < 7 ? rr : 7;
#pragma unroll
      for (int o = 0; o < 8; o++) {
        if (o >= olo && o <= ohi) acc[o] += v * wl[(rr - o) * 7 + kx];
      }
    }
  }
  int c = 32 + m;
  int cp = (c & 63) * 2 + (c >> 6);
  float* yp = y + ((long)b * CC + cp) * HWW;
#pragma unroll
  for (int o = 0; o < 8; o++) {
    yp[(r0 + s * 8 + o) * 128 + j] = acc[o];
  }
}

// ---------------- stats (bn1): two-stage ----------------------------------
__global__ __launch_bounds__(256) void k_stats1(
    const float* __restrict__ buf, float* __restrict__ part) {
  __shared__ float sh[256], sh2[256];
  int c = blockIdx.x >> 2, b = blockIdx.x & 3;
  int tid = threadIdx.x;
  const float* p = buf + ((long)b * CC + c) * HWW;
  float s = 0.f, s2 = 0.f;
  for (int it = 0; it < 16; it++) {
    float4 v = *(const float4*)(p + (it * 256 + tid) * 4);
    s += v.x + v.y + v.z + v.w;
    s2 += v.x * v.x + v.y * v.y + v.z * v.z + v.w * v.w;
  }
  sh[tid] = s; sh2[tid] = s2;
  __syncthreads();
  for (int o = 128; o > 0; o >>= 1) {
    if (tid < o) { sh[tid] += sh[tid + o]; sh2[tid] += sh2[tid + o]; }
    __syncthreads();
  }
  if (tid == 0) {
    part[blockIdx.x * 2] = sh[0];
    part[blockIdx.x * 2 + 1] = sh2[0];
  }
}

__global__ __launch_bounds__(128) void k_stats2(
    const float* __restrict__ part, float* __restrict__ mean, float* __restrict__ istd) {
  int c = threadIdx.x;
  float s = 0.f, s2 = 0.f;
#pragma unroll
  for (int b = 0; b < 4; b++) {
    s += part[(c * 4 + b) * 2];
    s2 += part[(c * 4 + b) * 2 + 1];
  }
  float mu = s * (1.f / 65536.f);
  float var = s2 * (1.f / 65536.f) - mu * mu;
  mean[c] = mu;
  istd[c] = rsqrtf(var + 1e-5f);
}

// ---------------- stats (bn2): finalize from atomic accumulators ----------
__global__ __launch_bounds__(128) void k_stats2b(
    const float* __restrict__ part2, float* __restrict__ mean, float* __restrict__ istd) {
  int c = threadIdx.x;
  float mu = part2[c] * (1.f / 65536.f);
  float var = part2[128 + c] * (1.f / 65536.f) - mu * mu;
  mean[c] = mu;
  istd[c] = rsqrtf(var + 1e-5f);
}

// ---------------- Kernel W: pre-swizzle w1/w2 into MFMA fragment order ----
__global__ __launch_bounds__(256) void k_wprep(
    const float* __restrict__ w1, const float* __restrict__ w2,
    unsigned short* __restrict__ w1b, unsigned short* __restrict__ w2b) {
  int t = blockIdx.x * 256 + threadIdx.x;
  int which = t >> 13;
  int u = t & 8191;
  int lane = u & 63;
  int ntks = u >> 6;
  int col = lane & 15, quad = lane >> 4;
  if (which == 0) {
    int nt = ntks >> 2, ks = ntks & 3;
    int n = nt * 16 + col;
    int k0 = ks * 32 + quad * 8;
    unsigned short* d = w1b + (long)u * 8;
#pragma unroll
    for (int j = 0; j < 8; j++) d[j] = f2us(w1[(long)(k0 + j) * 512 + n]);
  } else {
    int nt = ntks >> 4, ks = ntks & 15;
    int n = nt * 16 + col;
    int k0 = ks * 32 + quad * 8;
    unsigned short* d = w2b + (long)u * 8;
#pragma unroll
    for (int j = 0; j < 8; j++) d[j] = f2us(w2[(long)(k0 + j) * 128 + n]);
  }
}

// ---------------- Kernel F: BN1 + MLP via bf16 MFMA (H^T, barrier-free) ---
// GEMM1 computes H^T (W1-frags as A-operand, Y-frags as B) so the gelu'd
// chunk writes to Hs[tok][h] are contiguous in h -> us4 stores. Hs is
// per-wave; LDS ops complete in order per wave, so no in-loop barriers.
// Epilogue accumulates bn2 partial sums via LDS + global float atomics.
__global__ __launch_bounds__(256, 2) void k_mlp_mfma(
    const float* __restrict__ y, const float* __restrict__ mean1,
    const float* __restrict__ istd1, const float* __restrict__ g1,
    const float* __restrict__ b1n, const unsigned short* __restrict__ w1b,
    const float* __restrict__ b1, const unsigned short* __restrict__ w2b,
    const float* __restrict__ b2, float* __restrict__ tmid,
    float* __restrict__ part2) {
  __shared__ unsigned short At[128 * 136];
  __shared__ unsigned short Hs[4 * 32 * 72];
  __shared__ float scs[128], shs[128];
  __shared__ float ps[128], ps2[128];
  int tid = threadIdx.x;
  int lane = tid & 63, wv = tid >> 6;
  int row = lane & 15, quad = lane >> 4;  // row: 16-col/row index; quad: lane>>4
  int n0 = blockIdx.x * 128;
  int b = n0 >> 14;
  long base = (long)b * CC * HWW + (n0 & 16383);
  if (tid < 128) {
    float sc = istd1[tid] * g1[tid];
    scs[tid] = sc;
    shs[tid] = b1n[tid] - mean1[tid] * sc;
    ps[tid] = 0.f; ps2[tid] = 0.f;
  }
  __syncthreads();
  for (int it = 0; it < 16; it++) {
    int u = it * 256 + tid;
    int tok = u & 127, cg = u >> 7;
    us4 wvv;
#pragma unroll
    for (int r = 0; r < 4; r++) {
      int c = cg * 4 + r;
      float v = y[base + (long)c * HWW + tok];
      wvv[r] = f2us(v * scs[c] + shs[c]);
    }
    *(us4*)&At[tok * 136 + cg * 4] = wvv;
  }
  __syncthreads();
  bf16x8 Af[2][4];
#pragma unroll
  for (int mt = 0; mt < 2; mt++)
#pragma unroll
    for (int ks = 0; ks < 4; ks++)
      Af[mt][ks] = *(const bf16x8*)&At[(wv * 32 + mt * 16 + row) * 136 + ks * 32 + quad * 8];

  floatx4 Oa[2][8];
#pragma unroll
  for (int mt = 0; mt < 2; mt++)
#pragma unroll
    for (int nt = 0; nt < 8; nt++) Oa[mt][nt] = (floatx4)0.f;

  const int wvb = wv * 32 * 72;
  for (int ch = 0; ch < 8; ch++) {
    // GEMM1 (H^T): M = 64 hidden (4 tiles), N = 32 tokens (2 tiles)
    floatx4 Ha[4][2];
#pragma unroll
    for (int nt = 0; nt < 4; nt++)
#pragma unroll
      for (int mt = 0; mt < 2; mt++) Ha[nt][mt] = (floatx4)0.f;
#pragma unroll
    for (int nt = 0; nt < 4; nt++) {
      int ht = ch * 4 + nt;
#pragma unroll
      for (int ks = 0; ks < 4; ks++) {
        bf16x8 Wf = *(const bf16x8*)&w1b[(long)(((ht * 4 + ks) << 6) + lane) * 8];
        Ha[nt][0] = __builtin_amdgcn_mfma_f32_16x16x32_bf16(Wf, Af[0][ks], Ha[nt][0], 0, 0, 0);
        Ha[nt][1] = __builtin_amdgcn_mfma_f32_16x16x32_bf16(Wf, Af[1][ks], Ha[nt][1], 0, 0, 0);
      }
    }
    // epilogue: h = nt*16 + quad*4 + r (contiguous in r), tok = mt*16 + row
#pragma unroll
    for (int nt = 0; nt < 4; nt++) {
      float4 bb = *(const float4*)&b1[ch * 64 + nt * 16 + quad * 4];
#pragma unroll
      for (int mt = 0; mt < 2; mt++) {
        us4 hv;
        hv[0] = f2us(gelu_exact(Ha[nt][mt][0] + bb.x));
        hv[1] = f2us(gelu_exact(Ha[nt][mt][1] + bb.y));
        hv[2] = f2us(gelu_exact(Ha[nt][mt][2] + bb.z));
        hv[3] = f2us(gelu_exact(Ha[nt][mt][3] + bb.w));
        *(us4*)&Hs[wvb + (mt * 16 + row) * 72 + nt * 16 + quad * 4] = hv;
      }
    }
    // GEMM2: O += H[32 tok x 64 h] x W2[64 h x 128 c] — per-wave Hs, no barrier
    bf16x8 A2[2][2];
#pragma unroll
    for (int mt = 0; mt < 2; mt++)
#pragma unroll
      for (int ks = 0; ks < 2; ks++)
        A2[mt][ks] = *(const bf16x8*)&Hs[wvb + (mt * 16 + row) * 72 + ks * 32 + quad * 8];
#pragma unroll
    for (int nt = 0; nt < 8; nt++) {
#pragma unroll
      for (int ks = 0; ks < 2; ks++) {
        bf16x8 Bf = *(const bf16x8*)&w2b[(long)(((nt * 16 + ch * 2 + ks) << 6) + lane) * 8];
        Oa[0][nt] = __builtin_amdgcn_mfma_f32_16x16x32_bf16(A2[0][ks], Bf, Oa[0][nt], 0, 0, 0);
        Oa[1][nt] = __builtin_amdgcn_mfma_f32_16x16x32_bf16(A2[1][ks], Bf, Oa[1][nt], 0, 0, 0);
      }
    }
  }
  // final epilogue: +b2, store [c][tok] fp32, accumulate bn2 partials
#pragma unroll
  for (int nt = 0; nt < 8; nt++) {
    int c = nt * 16 + row;
    float bb = b2[c];
    long op = base + (long)c * HWW + wv * 32 + quad * 4;
    float s = 0.f, s2 = 0.f;
#pragma unroll
    for (int mt = 0; mt < 2; mt++) {
      floatx4 vv = Oa[mt][nt];
      vv[0] += bb; vv[1] += bb; vv[2] += bb; vv[3] += bb;
      *(floatx4*)&tmid[op + mt * 16] = vv;
      s += vv[0] + vv[1] + vv[2] + vv[3];
      s2 += vv[0] * vv[0] + vv[1] * vv[1] + vv[2] * vv[2] + vv[3] * vv[3];
    }
    atomicAdd(&ps[c], s);
    atomicAdd(&ps2[c], s2);
  }
  __syncthreads();
  if (tid < 128) {
    atomicAdd(&part2[tid], ps[tid]);
    atomicAdd(&part2[128 + tid], ps2[tid]);
  }
}

// ---------------- Kernel H: bn2 + residual + gelu (float4, in-place) ------
__global__ __launch_bounds__(256) void k_final(
    const float* __restrict__ x, const float* __restrict__ mean2,
    const float* __restrict__ istd2, const float* __restrict__ g2,
    const float* __restrict__ b2n, float* __restrict__ out) {
  long e4 = (long)blockIdx.x * 256 + threadIdx.x;
  int c = (int)((e4 >> 12) & 127);
  float sc = istd2[c] * g2[c];
  float sh = b2n[c] - mean2[c] * sc;
  float4 o = *(float4*)&out[e4 * 4];
  float4 xv = *(const float4*)&x[e4 * 4];
  o.x = gelu_exact(xv.x + o.x * sc + sh);
  o.y = gelu_exact(xv.y + o.y * sc + sh);
  o.z = gelu_exact(xv.z + o.z * sc + sh);
  o.w = gelu_exact(xv.w + o.w * sc + sh);
  *(float4*)&out[e4 * 4] = o;
}

extern "C" void kernel_launch(void* const* d_in, const int* in_sizes, int n_in,
                              void* d_out, int out_size, void* d_ws, size_t ws_size,
                              hipStream_t stream) {
  const float* x        = (const float*)d_in[0];
  const float* offset_w = (const float*)d_in[1];
  const float* offset_b = (const float*)d_in[2];
  const float* deform_w = (const float*)d_in[3];
  const float* dw_w     = (const float*)d_in[4];
  const float* dw_b     = (const float*)d_in[5];
  const float* dw2_w    = (const float*)d_in[6];
  const float* dw2_b    = (const float*)d_in[7];
  const float* bn1_g    = (const float*)d_in[8];
  const float* bn1_b    = (const float*)d_in[9];
  const float* w1       = (const float*)d_in[10];
  const float* b1       = (const float*)d_in[11];
  const float* w2       = (const float*)d_in[12];
  const float* b2       = (const float*)d_in[13];
  const float* bn2_g    = (const float*)d_in[14];
  const float* bn2_b    = (const float*)d_in[15];
  float* out = (float*)d_out;

  float* ws    = (float*)d_ws;
  float* off   = ws;                       // 1,179,648 f
  float* ybuf  = ws + 1179648;             // 8,388,608 f
  float* stats = ws + 9568256;             // 512 f
  float* mean1 = stats, *istd1 = stats + 128;
  float* mean2 = stats + 256, *istd2 = stats + 384;
  unsigned short* w1b = (unsigned short*)(ws + 9568768);  // 65,536 us
  unsigned short* w2b = (unsigned short*)(ws + 9601536);  // 65,536 us
  float* part  = ws + 9634304;             // 1,024 f
  float* xt    = ws + 9635328;             // 2,097,152 f
  unsigned short* wob = (unsigned short*)(ws + 11732480); // 9,216 us
  unsigned short* w3b = (unsigned short*)(ws + 11737088); // 9,216 us
  unsigned short* xp  = (unsigned short*)(ws + 11741696); // 4,460,544 us
  unsigned short* xp0 = xp;
  unsigned short* xp1 = xp + (long)4 * PREC * 32;
  float* part2 = ws + 13971968;            // 256 f (atomic bn2 accumulators)
  float* tmid  = out;

  k_zero<<<2179, 256, 0, stream>>>(xp, part2);
  k_wprep<<<64, 256, 0, stream>>>(w1, w2, w1b, w2b);
  k_wprep2<<<9, 256, 0, stream>>>(offset_w, dw2_w, wob, w3b);
  k_pack<<<2048, 256, 0, stream>>>(x, xp);
  k_xt<<<1024, 256, 0, stream>>>(x, xt);
  k_offc_mm<<<512, 256, 0, stream>>>(xp0, wob, offset_b, off);
  k_deform<<<512, 256, 0, stream>>>(xt, off, deform_w, ybuf);
  k_dw7<<<2048, 256, 0, stream>>>(x, dw_w, dw_b, ybuf);
  k_dil3_mm<<<512, 256, 0, stream>>>(xp1, w3b, dw2_b, ybuf);
  k_stats1<<<512, 256, 0, stream>>>(ybuf, part);
  k_stats2<<<1, 128, 0, stream>>>(part, mean1, istd1);
  k_mlp_mfma<<<512, 256, 0, stream>>>(ybuf, mean1, istd1, bn1_g, bn1_b, w1b, b1, w2b, b2, tmid, part2);
  k_stats2b<<<1, 128, 0, stream>>>(part2, mean2, istd2);
  k_final<<<8192, 256, 0, stream>>>(x, mean2, istd2, bn2_g, bn2_b, out);
}

// Round 10
// 277.710 us; speedup vs baseline: 1.0111x; 1.0111x over previous
//
#include <hip/hip_runtime.h>
#include <hip/hip_bf16.h>
#include <math.h>

#define BB 4
#define CC 128
#define HH 128
#define WWD 128
#define HWW 16384
#define PREC 17424  // 132*132 padded records per plane

typedef __attribute__((ext_vector_type(8))) short bf16x8;
typedef __attribute__((ext_vector_type(4))) float floatx4;
typedef __attribute__((ext_vector_type(4))) unsigned short us4;
typedef __attribute__((ext_vector_type(8))) unsigned short us8;

// tanh-form gelu: x*sigmoid(x*(1.5957691 + 0.0713548*x^2)).
// 8 VALU ops (v_exp_f32 + v_rcp_f32) vs ~50 for libm erff; |err| <= ~1e-3.
__device__ __forceinline__ float gelu_fast(float v) {
  float u = v * v;
  float z = v * fmaf(0.0713548163f, u, 1.5957691216f);
  float e = __builtin_amdgcn_exp2f(-1.4426950409f * z);
  return v * __builtin_amdgcn_rcpf(1.0f + e);
}
__device__ __forceinline__ unsigned short f2us(float f) {
  union { float f; unsigned int u; } c; c.f = f;
  unsigned int u = c.u;
  return (unsigned short)((u + 0x7FFFu + ((u >> 16) & 1u)) >> 16);
}

// ---------------- Kernel Z: zero padded planes + bn2 stat accumulators ----
__global__ __launch_bounds__(256) void k_zero(
    unsigned short* __restrict__ xp, float* __restrict__ part2) {
  if (blockIdx.x == 2178) { part2[threadIdx.x] = 0.f; return; }
  long i = ((long)blockIdx.x * 256 + threadIdx.x) * 8;
  us8 z = (us8)0;
  *(us8*)&xp[i] = z;
}

// ---------------- Kernel X: transpose x[:,0:32] -> xt[b][pixel][32] fp32 --
__global__ __launch_bounds__(256) void k_xt(
    const float* __restrict__ x, float* __restrict__ xt) {
  __shared__ float t[64 * 33];
  int bid = blockIdx.x;            // 1024: b = bid>>8, pg = bid&255
  int tid = threadIdx.x;
  int b = bid >> 8, pg = bid & 255;
  int c = tid >> 3, g8 = tid & 7;
  const float* xp = x + ((long)b * CC + c) * HWW + pg * 64 + g8 * 8;
  float4 v0 = *(const float4*)xp;
  float4 v1 = *(const float4*)(xp + 4);
  t[(g8 * 8 + 0) * 33 + c] = v0.x; t[(g8 * 8 + 1) * 33 + c] = v0.y;
  t[(g8 * 8 + 2) * 33 + c] = v0.z; t[(g8 * 8 + 3) * 33 + c] = v0.w;
  t[(g8 * 8 + 4) * 33 + c] = v1.x; t[(g8 * 8 + 5) * 33 + c] = v1.y;
  t[(g8 * 8 + 6) * 33 + c] = v1.z; t[(g8 * 8 + 7) * 33 + c] = v1.w;
  __syncthreads();
  int u = tid >> 2, q = tid & 3;
  float4 o0, o1;
  o0.x = t[u * 33 + q * 8 + 0]; o0.y = t[u * 33 + q * 8 + 1];
  o0.z = t[u * 33 + q * 8 + 2]; o0.w = t[u * 33 + q * 8 + 3];
  o1.x = t[u * 33 + q * 8 + 4]; o1.y = t[u * 33 + q * 8 + 5];
  o1.z = t[u * 33 + q * 8 + 6]; o1.w = t[u * 33 + q * 8 + 7];
  float* d = xt + ((long)b * HWW + pg * 64 + u) * 32 + q * 8;
  *(float4*)d = o0;
  *(float4*)(d + 4) = o1;
}

// ---------------- Kernel P: pack padded channels-last bf16 planes ---------
__global__ __launch_bounds__(256) void k_pack(
    const float* __restrict__ x, unsigned short* __restrict__ xp) {
  __shared__ float t[64 * 33];
  int bid = blockIdx.x;            // 2048 = which(2) x b(4) x pg(256)
  int tid = threadIdx.x;
  int which = bid >> 10, b = (bid >> 8) & 3, pg = bid & 255;
  int cbase = which ? 96 : 0;
  int c = tid >> 3, g8 = tid & 7;
  const float* xpr = x + ((long)b * CC + cbase + c) * HWW + pg * 64 + g8 * 8;
  float4 v0 = *(const float4*)xpr;
  float4 v1 = *(const float4*)(xpr + 4);
  t[(g8 * 8 + 0) * 33 + c] = v0.x; t[(g8 * 8 + 1) * 33 + c] = v0.y;
  t[(g8 * 8 + 2) * 33 + c] = v0.z; t[(g8 * 8 + 3) * 33 + c] = v0.w;
  t[(g8 * 8 + 4) * 33 + c] = v1.x; t[(g8 * 8 + 5) * 33 + c] = v1.y;
  t[(g8 * 8 + 6) * 33 + c] = v1.z; t[(g8 * 8 + 7) * 33 + c] = v1.w;
  __syncthreads();
  int u = tid >> 2, q = tid & 3;
  int p = pg * 64 + u;
  int yy = p >> 7, xx = p & 127;
  long rec = (long)(which * 4 + b) * PREC + (yy + 2) * 132 + xx + 2;
  us8 o;
#pragma unroll
  for (int k = 0; k < 8; k++) o[k] = f2us(t[u * 33 + q * 8 + k]);
  *(us8*)&xp[rec * 32 + q * 8] = o;
}

// ---------------- Kernel W2: conv weights -> MFMA B-fragment order --------
__global__ __launch_bounds__(256) void k_wprep2(
    const float* __restrict__ offw, const float* __restrict__ dilw,
    unsigned short* __restrict__ wob, unsigned short* __restrict__ w3b) {
  int t = blockIdx.x * 256 + threadIdx.x;  // 0..2303
  if (t >= 2304) return;
  int which = t >= 1152;
  int u = t - which * 1152;
  int lane = u & 63, tn = u >> 6;          // tn = tap*2 + nt
  int col = lane & 15, quad = lane >> 4;
  int tap = tn >> 1, nt = tn & 1;
  int n = nt * 16 + col;
  const float* W = which ? dilw : offw;
  int noc = which ? 32 : 18;
  unsigned short* d = (which ? w3b : wob) + (long)(tn * 64 + lane) * 8;
#pragma unroll
  for (int j = 0; j < 8; j++)
    d[j] = (n < noc) ? f2us(W[(long)n * 288 + (quad * 8 + j) * 9 + tap]) : (unsigned short)0;
}

// ---------------- Kernel A: offset conv 3x3 via MFMA implicit GEMM --------
__global__ __launch_bounds__(256) void k_offc_mm(
    const unsigned short* __restrict__ xp0, const unsigned short* __restrict__ wob,
    const float* __restrict__ bias, float* __restrict__ off) {
  int bid = blockIdx.x;
  int b = bid >> 7, yy = bid & 127;
  int tid = threadIdx.x;
  int lane = tid & 63, wv = tid >> 6;
  int row = lane & 15, quad = lane >> 4;
  const unsigned short* plane = xp0 + (long)b * PREC * 32;
  int xb = wv * 32;
  floatx4 Oa[2][2];
#pragma unroll
  for (int mt = 0; mt < 2; mt++)
#pragma unroll
    for (int nt = 0; nt < 2; nt++) Oa[mt][nt] = (floatx4)0.f;
#pragma unroll
  for (int t = 0; t < 9; t++) {
    int dy = t / 3 - 1, dx = t % 3 - 1;
    const unsigned short* rp = plane + ((long)(yy + 2 + dy) * 132 + 2 + dx + xb) * 32;
    bf16x8 A0 = *(const bf16x8*)&rp[row * 32 + quad * 8];
    bf16x8 A1 = *(const bf16x8*)&rp[(16 + row) * 32 + quad * 8];
#pragma unroll
    for (int nt = 0; nt < 2; nt++) {
      bf16x8 Bf = *(const bf16x8*)&wob[(long)((t * 2 + nt) * 64 + lane) * 8];
      Oa[0][nt] = __builtin_amdgcn_mfma_f32_16x16x32_bf16(A0, Bf, Oa[0][nt], 0, 0, 0);
      Oa[1][nt] = __builtin_amdgcn_mfma_f32_16x16x32_bf16(A1, Bf, Oa[1][nt], 0, 0, 0);
    }
  }
#pragma unroll
  for (int nt = 0; nt < 2; nt++) {
    int oc = nt * 16 + (lane & 15);
    if (oc < 18) {
      float bb = bias[oc];
#pragma unroll
      for (int mt = 0; mt < 2; mt++) {
        floatx4 v = Oa[mt][nt];
        v[0] += bb; v[1] += bb; v[2] += bb; v[3] += bb;
        long p = (long)(b * 18 + oc) * HWW + yy * 128 + xb + mt * 16 + quad * 4;
        *(floatx4*)&off[p] = v;
      }
    }
  }
}

// ---------------- Kernel D: dilated 3x3 conv via MFMA implicit GEMM -------
__global__ __launch_bounds__(256) void k_dil3_mm(
    const unsigned short* __restrict__ xp1, const unsigned short* __restrict__ w3b,
    const float* __restrict__ bias, float* __restrict__ y) {
  int bid = blockIdx.x;
  int b = bid >> 7, yy = bid & 127;
  int tid = threadIdx.x;
  int lane = tid & 63, wv = tid >> 6;
  int row = lane & 15, quad = lane >> 4;
  const unsigned short* plane = xp1 + (long)b * PREC * 32;
  int xb = wv * 32;
  floatx4 Oa[2][2];
#pragma unroll
  for (int mt = 0; mt < 2; mt++)
#pragma unroll
    for (int nt = 0; nt < 2; nt++) Oa[mt][nt] = (floatx4)0.f;
#pragma unroll
  for (int t = 0; t < 9; t++) {
    int dy = (t / 3 - 1) * 2, dx = (t % 3 - 1) * 2;
    const unsigned short* rp = plane + ((long)(yy + 2 + dy) * 132 + 2 + dx + xb) * 32;
    bf16x8 A0 = *(const bf16x8*)&rp[row * 32 + quad * 8];
    bf16x8 A1 = *(const bf16x8*)&rp[(16 + row) * 32 + quad * 8];
#pragma unroll
    for (int nt = 0; nt < 2; nt++) {
      bf16x8 Bf = *(const bf16x8*)&w3b[(long)((t * 2 + nt) * 64 + lane) * 8];
      Oa[0][nt] = __builtin_amdgcn_mfma_f32_16x16x32_bf16(A0, Bf, Oa[0][nt], 0, 0, 0);
      Oa[1][nt] = __builtin_amdgcn_mfma_f32_16x16x32_bf16(A1, Bf, Oa[1][nt], 0, 0, 0);
    }
  }
#pragma unroll
  for (int nt = 0; nt < 2; nt++) {
    int oc = nt * 16 + (lane & 15);
    int cp = 65 + 2 * oc;   // c = 96+oc -> (c%64)*2 + c/64
    float bb = bias[oc];
#pragma unroll
    for (int mt = 0; mt < 2; mt++) {
      floatx4 v = Oa[mt][nt];
      v[0] += bb; v[1] += bb; v[2] += bb; v[3] += bb;
      long p = ((long)b * CC + cp) * HWW + yy * 128 + xb + mt * 16 + quad * 4;
      *(floatx4*)&y[p] = v;
    }
  }
}

// ---------------- Kernel B: deformable depthwise, channels-last gathers ---
__global__ __launch_bounds__(256) void k_deform(
    const float* __restrict__ xt, const float* __restrict__ off,
    const float* __restrict__ dw, float* __restrict__ y) {
  __shared__ float wl[144];        // [k][16]
  int tid = threadIdx.x;
  int g = blockIdx.x * 256 + tid;
  int hf = g >> 16;                // uniform per block
  int pix = g & 65535;
  if (tid < 144) {
    int k = tid >> 4, q = tid & 15;
    wl[k * 16 + q] = dw[(hf * 16 + q) * 9 + k];
  }
  __syncthreads();
  int b = pix >> 14, p = pix & 16383;
  int i = p >> 7, j = p & 127;
  float acc[16];
#pragma unroll
  for (int q = 0; q < 16; q++) acc[q] = 0.f;
  const float* offb = off + (long)b * 18 * HWW + p;
  const float* xb = xt + (long)b * HWW * 32 + hf * 16;
  for (int k = 0; k < 9; k++) {
    float dy = offb[(long)(2 * k) * HWW];
    float dx = offb[(long)(2 * k + 1) * HWW];
    float ys = (float)i - 1.f + (float)(k / 3) + dy;
    float xs = (float)j - 1.f + (float)(k % 3) + dx;
    float y0 = floorf(ys), x0 = floorf(xs);
    float fy = ys - y0, fx = xs - x0;
    int iy0 = (int)y0, ix0 = (int)x0;
    int iy1 = iy0 + 1, ix1 = ix0 + 1;
    float wy0 = (1.f - fy) * ((iy0 >= 0 && iy0 <= 127) ? 1.f : 0.f);
    float wy1 = fy * ((iy1 >= 0 && iy1 <= 127) ? 1.f : 0.f);
    float wx0 = (1.f - fx) * ((ix0 >= 0 && ix0 <= 127) ? 1.f : 0.f);
    float wx1 = fx * ((ix1 >= 0 && ix1 <= 127) ? 1.f : 0.f);
    int cy0 = min(max(iy0, 0), 127), cy1 = min(max(iy1, 0), 127);
    int cx0 = min(max(ix0, 0), 127), cx1 = min(max(ix1, 0), 127);
    int ci[4] = {cy0 * 128 + cx0, cy0 * 128 + cx1, cy1 * 128 + cx0, cy1 * 128 + cx1};
    float cw[4] = {wy0 * wx0, wy0 * wx1, wy1 * wx0, wy1 * wx1};
    float v[16];
#pragma unroll
    for (int q = 0; q < 16; q++) v[q] = 0.f;
#pragma unroll
    for (int cn = 0; cn < 4; cn++) {
      const float* cp = xb + (long)ci[cn] * 32;
      float wc = cw[cn];
      float4 p0 = *(const float4*)cp;
      float4 p1 = *(const float4*)(cp + 4);
      float4 p2 = *(const float4*)(cp + 8);
      float4 p3 = *(const float4*)(cp + 12);
      v[0] += wc * p0.x;  v[1] += wc * p0.y;  v[2] += wc * p0.z;  v[3] += wc * p0.w;
      v[4] += wc * p1.x;  v[5] += wc * p1.y;  v[6] += wc * p1.z;  v[7] += wc * p1.w;
      v[8] += wc * p2.x;  v[9] += wc * p2.y;  v[10] += wc * p2.z; v[11] += wc * p2.w;
      v[12] += wc * p3.x; v[13] += wc * p3.y; v[14] += wc * p3.z; v[15] += wc * p3.w;
    }
    const float* wr = &wl[k * 16];
#pragma unroll
    for (int q = 0; q < 16; q++) acc[q] += wr[q] * v[q];
  }
#pragma unroll
  for (int q = 0; q < 16; q++) {
    int cp = 2 * (hf * 16 + q);
    y[((long)b * CC + cp) * HWW + p] = acc[q];
  }
}

// ---------------- Kernel C: depthwise 7x7, LDS-tiled ----------------------
__global__ __launch_bounds__(256) void k_dw7(
    const float* __restrict__ x, const float* __restrict__ w,
    const float* __restrict__ bias, float* __restrict__ y) {
  __shared__ float tile[22 * 136];
  __shared__ float wl[49];
  __shared__ float bsh;
  int bid = blockIdx.x;
  int b = bid >> 9, m = (bid >> 3) & 63, strip = bid & 7;
  int r0 = strip * 16;
  int tid = threadIdx.x;
  const float* xp = x + ((long)b * CC + 32 + m) * HWW;
  for (int idx = tid; idx < 2948; idx += 256) {
    int rr = idx / 134;
    int cc = idx - rr * 134 - 3;
    int gy = r0 - 3 + rr;
    float v = 0.f;
    if ((unsigned)gy < 128u && (unsigned)cc < 128u) v = xp[gy * 128 + cc];
    tile[rr * 136 + cc + 3] = v;
  }
  if (tid < 49) wl[tid] = w[m * 49 + tid];
  if (tid == 64) bsh = bias[m];
  __syncthreads();
  int j = tid & 127, s = tid >> 7;
  float acc[8];
#pragma unroll
  for (int o = 0; o < 8; o++) acc[o] = bsh;
#pragma unroll
  for (int kx = 0; kx < 7; kx++) {
#pragma unroll
    for (int rr = 0; rr < 14; rr++) {
      float v = tile[(s * 8 + rr) * 136 + j + kx];
      int olo = rr - 6 > 0 ? rr - 6 : 0;
      int ohi = rr < 7 ? rr : 7;
#pragma unroll
      for (int o = 0; o < 8; o++) {
        if (o >= olo && o <= ohi) acc[o] += v * wl[(rr - o) * 7 + kx];
      }
    }
  }
  int c = 32 + m;
  int cp = (c & 63) * 2 + (c >> 6);
  float* yp = y + ((long)b * CC + cp) * HWW;
#pragma unroll
  for (int o = 0; o < 8; o++) {
    yp[(r0 + s * 8 + o) * 128 + j] = acc[o];
  }
}

// ---------------- stats (bn1): two-stage ----------------------------------
__global__ __launch_bounds__(256) void k_stats1(
    const float* __restrict__ buf, float* __restrict__ part) {
  __shared__ float sh[256], sh2[256];
  int c = blockIdx.x >> 2, b = blockIdx.x & 3;
  int tid = threadIdx.x;
  const float* p = buf + ((long)b * CC + c) * HWW;
  float s = 0.f, s2 = 0.f;
  for (int it = 0; it < 16; it++) {
    float4 v = *(const float4*)(p + (it * 256 + tid) * 4);
    s += v.x + v.y + v.z + v.w;
    s2 += v.x * v.x + v.y * v.y + v.z * v.z + v.w * v.w;
  }
  sh[tid] = s; sh2[tid] = s2;
  __syncthreads();
  for (int o = 128; o > 0; o >>= 1) {
    if (tid < o) { sh[tid] += sh[tid + o]; sh2[tid] += sh2[tid + o]; }
    __syncthreads();
  }
  if (tid == 0) {
    part[blockIdx.x * 2] = sh[0];
    part[blockIdx.x * 2 + 1] = sh2[0];
  }
}

__global__ __launch_bounds__(128) void k_stats2(
    const float* __restrict__ part, float* __restrict__ mean, float* __restrict__ istd) {
  int c = threadIdx.x;
  float s = 0.f, s2 = 0.f;
#pragma unroll
  for (int b = 0; b < 4; b++) {
    s += part[(c * 4 + b) * 2];
    s2 += part[(c * 4 + b) * 2 + 1];
  }
  float mu = s * (1.f / 65536.f);
  float var = s2 * (1.f / 65536.f) - mu * mu;
  mean[c] = mu;
  istd[c] = rsqrtf(var + 1e-5f);
}

// ---------------- stats (bn2): finalize from atomic accumulators ----------
__global__ __launch_bounds__(128) void k_stats2b(
    const float* __restrict__ part2, float* __restrict__ mean, float* __restrict__ istd) {
  int c = threadIdx.x;
  float mu = part2[c] * (1.f / 65536.f);
  float var = part2[128 + c] * (1.f / 65536.f) - mu * mu;
  mean[c] = mu;
  istd[c] = rsqrtf(var + 1e-5f);
}

// ---------------- Kernel W: pre-swizzle w1/w2 into MFMA fragment order ----
__global__ __launch_bounds__(256) void k_wprep(
    const float* __restrict__ w1, const float* __restrict__ w2,
    unsigned short* __restrict__ w1b, unsigned short* __restrict__ w2b) {
  int t = blockIdx.x * 256 + threadIdx.x;
  int which = t >> 13;
  int u = t & 8191;
  int lane = u & 63;
  int ntks = u >> 6;
  int col = lane & 15, quad = lane >> 4;
  if (which == 0) {
    int nt = ntks >> 2, ks = ntks & 3;
    int n = nt * 16 + col;
    int k0 = ks * 32 + quad * 8;
    unsigned short* d = w1b + (long)u * 8;
#pragma unroll
    for (int j = 0; j < 8; j++) d[j] = f2us(w1[(long)(k0 + j) * 512 + n]);
  } else {
    int nt = ntks >> 4, ks = ntks & 15;
    int n = nt * 16 + col;
    int k0 = ks * 32 + quad * 8;
    unsigned short* d = w2b + (long)u * 8;
#pragma unroll
    for (int j = 0; j < 8; j++) d[j] = f2us(w2[(long)(k0 + j) * 128 + n]);
  }
}

// ---------------- Kernel F: BN1 + MLP via bf16 MFMA (H^T + fast gelu) -----
// GEMM1 computes H^T so gelu'd writes to Hs[tok][h] are contiguous (us4).
// Per-chunk barriers restored: round-9 measured removing them costs ~12 µs
// (wave phase drift), even though Hs is per-wave and they're not needed for
// correctness. bn2 partial stats fused in epilogue.
__global__ __launch_bounds__(256, 2) void k_mlp_mfma(
    const float* __restrict__ y, const float* __restrict__ mean1,
    const float* __restrict__ istd1, const float* __restrict__ g1,
    const float* __restrict__ b1n, const unsigned short* __restrict__ w1b,
    const float* __restrict__ b1, const unsigned short* __restrict__ w2b,
    const float* __restrict__ b2, float* __restrict__ tmid,
    float* __restrict__ part2) {
  __shared__ unsigned short At[128 * 136];
  __shared__ unsigned short Hs[4 * 32 * 72];
  __shared__ float scs[128], shs[128];
  __shared__ float ps[128], ps2[128];
  int tid = threadIdx.x;
  int lane = tid & 63, wv = tid >> 6;
  int row = lane & 15, quad = lane >> 4;
  int n0 = blockIdx.x * 128;
  int b = n0 >> 14;
  long base = (long)b * CC * HWW + (n0 & 16383);
  if (tid < 128) {
    float sc = istd1[tid] * g1[tid];
    scs[tid] = sc;
    shs[tid] = b1n[tid] - mean1[tid] * sc;
    ps[tid] = 0.f; ps2[tid] = 0.f;
  }
  __syncthreads();
  for (int it = 0; it < 16; it++) {
    int u = it * 256 + tid;
    int tok = u & 127, cg = u >> 7;
    us4 wvv;
#pragma unroll
    for (int r = 0; r < 4; r++) {
      int c = cg * 4 + r;
      float v = y[base + (long)c * HWW + tok];
      wvv[r] = f2us(v * scs[c] + shs[c]);
    }
    *(us4*)&At[tok * 136 + cg * 4] = wvv;
  }
  __syncthreads();
  bf16x8 Af[2][4];
#pragma unroll
  for (int mt = 0; mt < 2; mt++)
#pragma unroll
    for (int ks = 0; ks < 4; ks++)
      Af[mt][ks] = *(const bf16x8*)&At[(wv * 32 + mt * 16 + row) * 136 + ks * 32 + quad * 8];

  floatx4 Oa[2][8];
#pragma unroll
  for (int mt = 0; mt < 2; mt++)
#pragma unroll
    for (int nt = 0; nt < 8; nt++) Oa[mt][nt] = (floatx4)0.f;

  const int wvb = wv * 32 * 72;
  for (int ch = 0; ch < 8; ch++) {
    // GEMM1 (H^T): M = 64 hidden (4 tiles), N = 32 tokens (2 tiles)
    floatx4 Ha[4][2];
#pragma unroll
    for (int nt = 0; nt < 4; nt++)
#pragma unroll
      for (int mt = 0; mt < 2; mt++) Ha[nt][mt] = (floatx4)0.f;
#pragma unroll
    for (int nt = 0; nt < 4; nt++) {
      int ht = ch * 4 + nt;
#pragma unroll
      for (int ks = 0; ks < 4; ks++) {
        bf16x8 Wf = *(const bf16x8*)&w1b[(long)(((ht * 4 + ks) << 6) + lane) * 8];
        Ha[nt][0] = __builtin_amdgcn_mfma_f32_16x16x32_bf16(Wf, Af[0][ks], Ha[nt][0], 0, 0, 0);
        Ha[nt][1] = __builtin_amdgcn_mfma_f32_16x16x32_bf16(Wf, Af[1][ks], Ha[nt][1], 0, 0, 0);
      }
    }
    // epilogue: h = nt*16 + quad*4 + r (contiguous in r), tok = mt*16 + row
#pragma unroll
    for (int nt = 0; nt < 4; nt++) {
      float4 bb = *(const float4*)&b1[ch * 64 + nt * 16 + quad * 4];
#pragma unroll
      for (int mt = 0; mt < 2; mt++) {
        us4 hv;
        hv[0] = f2us(gelu_fast(Ha[nt][mt][0] + bb.x));
        hv[1] = f2us(gelu_fast(Ha[nt][mt][1] + bb.y));
        hv[2] = f2us(gelu_fast(Ha[nt][mt][2] + bb.z));
        hv[3] = f2us(gelu_fast(Ha[nt][mt][3] + bb.w));
        *(us4*)&Hs[wvb + (mt * 16 + row) * 72 + nt * 16 + quad * 4] = hv;
      }
    }
    __syncthreads();  // phase-lock waves (scheduling aid; Hs is per-wave)
    // GEMM2: O += H[32 tok x 64 h] x W2[64 h x 128 c]
    bf16x8 A2[2][2];
#pragma unroll
    for (int mt = 0; mt < 2; mt++)
#pragma unroll
      for (int ks = 0; ks < 2; ks++)
        A2[mt][ks] = *(const bf16x8*)&Hs[wvb + (mt * 16 + row) * 72 + ks * 32 + quad * 8];
#pragma unroll
    for (int nt = 0; nt < 8; nt++) {
#pragma unroll
      for (int ks = 0; ks < 2; ks++) {
        bf16x8 Bf = *(const bf16x8*)&w2b[(long)(((nt * 16 + ch * 2 + ks) << 6) + lane) * 8];
        Oa[0][nt] = __builtin_amdgcn_mfma_f32_16x16x32_bf16(A2[0][ks], Bf, Oa[0][nt], 0, 0, 0);
        Oa[1][nt] = __builtin_amdgcn_mfma_f32_16x16x32_bf16(A2[1][ks], Bf, Oa[1][nt], 0, 0, 0);
      }
    }
    __syncthreads();
  }
  // final epilogue: +b2, store [c][tok] fp32, accumulate bn2 partials
#pragma unroll
  for (int nt = 0; nt < 8; nt++) {
    int c = nt * 16 + row;
    float bb = b2[c];
    long op = base + (long)c * HWW + wv * 32 + quad * 4;
    float s = 0.f, s2 = 0.f;
#pragma unroll
    for (int mt = 0; mt < 2; mt++) {
      floatx4 vv = Oa[mt][nt];
      vv[0] += bb; vv[1] += bb; vv[2] += bb; vv[3] += bb;
      *(floatx4*)&tmid[op + mt * 16] = vv;
      s += vv[0] + vv[1] + vv[2] + vv[3];
      s2 += vv[0] * vv[0] + vv[1] * vv[1] + vv[2] * vv[2] + vv[3] * vv[3];
    }
    atomicAdd(&ps[c], s);
    atomicAdd(&ps2[c], s2);
  }
  __syncthreads();
  if (tid < 128) {
    atomicAdd(&part2[tid], ps[tid]);
    atomicAdd(&part2[128 + tid], ps2[tid]);
  }
}

// ---------------- Kernel H: bn2 + residual + gelu (float4, in-place) ------
__global__ __launch_bounds__(256) void k_final(
    const float* __restrict__ x, const float* __restrict__ mean2,
    const float* __restrict__ istd2, const float* __restrict__ g2,
    const float* __restrict__ b2n, float* __restrict__ out) {
  long e4 = (long)blockIdx.x * 256 + threadIdx.x;
  int c = (int)((e4 >> 12) & 127);
  float sc = istd2[c] * g2[c];
  float sh = b2n[c] - mean2[c] * sc;
  float4 o = *(float4*)&out[e4 * 4];
  float4 xv = *(const float4*)&x[e4 * 4];
  o.x = gelu_fast(xv.x + o.x * sc + sh);
  o.y = gelu_fast(xv.y + o.y * sc + sh);
  o.z = gelu_fast(xv.z + o.z * sc + sh);
  o.w = gelu_fast(xv.w + o.w * sc + sh);
  *(float4*)&out[e4 * 4] = o;
}

extern "C" void kernel_launch(void* const* d_in, const int* in_sizes, int n_in,
                              void* d_out, int out_size, void* d_ws, size_t ws_size,
                              hipStream_t stream) {
  const float* x        = (const float*)d_in[0];
  const float* offset_w = (const float*)d_in[1];
  const float* offset_b = (const float*)d_in[2];
  const float* deform_w = (const float*)d_in[3];
  const float* dw_w     = (const float*)d_in[4];
  const float* dw_b     = (const float*)d_in[5];
  const float* dw2_w    = (const float*)d_in[6];
  const float* dw2_b    = (const float*)d_in[7];
  const float* bn1_g    = (const float*)d_in[8];
  const float* bn1_b    = (const float*)d_in[9];
  const float* w1       = (const float*)d_in[10];
  const float* b1       = (const float*)d_in[11];
  const float* w2       = (const float*)d_in[12];
  const float* b2       = (const float*)d_in[13];
  const float* bn2_g    = (const float*)d_in[14];
  const float* bn2_b    = (const float*)d_in[15];
  float* out = (float*)d_out;

  float* ws    = (float*)d_ws;
  float* off   = ws;                       // 1,179,648 f
  float* ybuf  = ws + 1179648;             // 8,388,608 f
  float* stats = ws + 9568256;             // 512 f
  float* mean1 = stats, *istd1 = stats + 128;
  float* mean2 = stats + 256, *istd2 = stats + 384;
  unsigned short* w1b = (unsigned short*)(ws + 9568768);  // 65,536 us
  unsigned short* w2b = (unsigned short*)(ws + 9601536);  // 65,536 us
  float* part  = ws + 9634304;             // 1,024 f
  float* xt    = ws + 9635328;             // 2,097,152 f
  unsigned short* wob = (unsigned short*)(ws + 11732480); // 9,216 us
  unsigned short* w3b = (unsigned short*)(ws + 11737088); // 9,216 us
  unsigned short* xp  = (unsigned short*)(ws + 11741696); // 4,460,544 us
  unsigned short* xp0 = xp;
  unsigned short* xp1 = xp + (long)4 * PREC * 32;
  float* part2 = ws + 13971968;            // 256 f (atomic bn2 accumulators)
  float* tmid  = out;

  k_zero<<<2179, 256, 0, stream>>>(xp, part2);
  k_wprep<<<64, 256, 0, stream>>>(w1, w2, w1b, w2b);
  k_wprep2<<<9, 256, 0, stream>>>(offset_w, dw2_w, wob, w3b);
  k_pack<<<2048, 256, 0, stream>>>(x, xp);
  k_xt<<<1024, 256, 0, stream>>>(x, xt);
  k_offc_mm<<<512, 256, 0, stream>>>(xp0, wob, offset_b, off);
  k_deform<<<512, 256, 0, stream>>>(xt, off, deform_w, ybuf);
  k_dw7<<<2048, 256, 0, stream>>>(x, dw_w, dw_b, ybuf);
  k_dil3_mm<<<512, 256, 0, stream>>>(xp1, w3b, dw2_b, ybuf);
  k_stats1<<<512, 256, 0, stream>>>(ybuf, part);
  k_stats2<<<1, 128, 0, stream>>>(part, mean1, istd1);
  k_mlp_mfma<<<512, 256, 0, stream>>>(ybuf, mean1, istd1, bn1_g, bn1_b, w1b, b1, w2b, b2, tmid, part2);
  k_stats2b<<<1, 128, 0, stream>>>(part2, mean2, istd2);
  k_final<<<8192, 256, 0, stream>>>(x, mean2, istd2, bn2_g, bn2_b, out);
}